// Round 1
// baseline (81.598 us; speedup 1.0000x reference)
//
#include <hip/hip_runtime.h>

// Problem shape (fixed by reference): B=8, C=21, H=512, W=512, fp32.
#define HW_ELEMS (512 * 512)
#define C_CLASSES 21
#define B_BATCH 8
#define BLOCKS_PER_PLANE 16
#define THREADS 256

// ws layout: 21 classes x {pred_cnt, target_cnt, inter_cnt} as uint32.
// Max count per class = B*H*W = 2,097,152 < 2^32 -> uint32 is safe.

__global__ __launch_bounds__(THREADS) void jaccard_count(
    const float* __restrict__ preds,
    const float* __restrict__ target,
    unsigned int* __restrict__ ws) {
  const int bid = blockIdx.x;
  const int plane = bid / BLOCKS_PER_PLANE;  // = b*C + c, 0..167
  const int chunk = bid % BLOCKS_PER_PLANE;
  const int c = plane % C_CLASSES;

  const long long chunk_elems = HW_ELEMS / BLOCKS_PER_PLANE;  // 16384
  const long long base = (long long)plane * HW_ELEMS + (long long)chunk * chunk_elems;

  const float4* __restrict__ p4 = (const float4*)(preds + base);
  const float4* __restrict__ t4 = (const float4*)(target + base);
  const int nvec = (int)(chunk_elems / 4);  // 4096 float4 per block

  unsigned int pc = 0, tc = 0, ic = 0;
#pragma unroll 4
  for (int i = threadIdx.x; i < nvec; i += THREADS) {
    const float4 p = p4[i];
    const float4 t = t4[i];
    {
      const unsigned pb = (p.x >= 0.5f), tb = (t.x == 1.0f);
      pc += pb; tc += tb; ic += pb & tb;
    }
    {
      const unsigned pb = (p.y >= 0.5f), tb = (t.y == 1.0f);
      pc += pb; tc += tb; ic += pb & tb;
    }
    {
      const unsigned pb = (p.z >= 0.5f), tb = (t.z == 1.0f);
      pc += pb; tc += tb; ic += pb & tb;
    }
    {
      const unsigned pb = (p.w >= 0.5f), tb = (t.w == 1.0f);
      pc += pb; tc += tb; ic += pb & tb;
    }
  }

  // Wave64 butterfly reduce.
#pragma unroll
  for (int off = 32; off > 0; off >>= 1) {
    pc += __shfl_down(pc, off, 64);
    tc += __shfl_down(tc, off, 64);
    ic += __shfl_down(ic, off, 64);
  }

  __shared__ unsigned int s[3][THREADS / 64];
  const int wave = threadIdx.x >> 6;
  const int lane = threadIdx.x & 63;
  if (lane == 0) {
    s[0][wave] = pc;
    s[1][wave] = tc;
    s[2][wave] = ic;
  }
  __syncthreads();
  if (threadIdx.x == 0) {
    unsigned int P = 0, T = 0, I = 0;
#pragma unroll
    for (int w = 0; w < THREADS / 64; ++w) {
      P += s[0][w];
      T += s[1][w];
      I += s[2][w];
    }
    atomicAdd(&ws[c * 3 + 0], P);
    atomicAdd(&ws[c * 3 + 1], T);
    atomicAdd(&ws[c * 3 + 2], I);
  }
}

__global__ void jaccard_finalize(const unsigned int* __restrict__ ws,
                                 float* __restrict__ out) {
  const int c = threadIdx.x;
  if (c < C_CLASSES) {
    const float P = (float)ws[c * 3 + 0];
    const float T = (float)ws[c * 3 + 1];
    const float I = (float)ws[c * 3 + 2];
    const float U = P + T - I;
    out[c] = (U == 0.0f) ? __uint_as_float(0x7FC00000u) : I / fmaxf(U, 1.0f);
  }
}

extern "C" void kernel_launch(void* const* d_in, const int* in_sizes, int n_in,
                              void* d_out, int out_size, void* d_ws, size_t ws_size,
                              hipStream_t stream) {
  const float* preds = (const float*)d_in[0];
  const float* target = (const float*)d_in[1];
  unsigned int* ws = (unsigned int*)d_ws;
  float* out = (float*)d_out;

  hipMemsetAsync(ws, 0, C_CLASSES * 3 * sizeof(unsigned int), stream);

  const int grid = B_BATCH * C_CLASSES * BLOCKS_PER_PLANE;  // 2688 blocks
  jaccard_count<<<grid, THREADS, 0, stream>>>(preds, target, ws);
  jaccard_finalize<<<1, 64, 0, stream>>>(ws, out);
}